// Round 1
// baseline (21282.959 us; speedup 1.0000x reference)
//
#include <hip/hip_runtime.h>

// Problem constants (fixed by the reference):
//   B=8, N=16384 (H=W=128), D=128, WS=4 -> nW=1024 windows/batch, P=16 tok/window
//   NH=2 heads, dh=64.  All fp32.
#define NTOK 16384
#define DD   128

__device__ __forceinline__ float gelu_exact(float x) {
    return 0.5f * x * (1.0f + erff(x * 0.7071067811865475f));
}

// ---------------------------------------------------------------------------
// Fused windowed-MHSA kernel. One block (256 thr) per window (B*1024 blocks).
// BRANCH==1: x1=LN1(x) gathered in IMAGE order; epilogue res1 = trunc(x[n]) + a1[n]
//            with n = window-order flat index (the reference's quirk).
// BRANCH==2: input gathered from out1 at roll-mapped index m; epilogue
//            res2[m] = out1[m] + attn_out  (gather index == scatter index).
// ---------------------------------------------------------------------------
template <int BRANCH>
__global__ __launch_bounds__(256, 2)
void attn_kernel(const float* __restrict__ xin,   // LN source buffer [B,N,D]
                 const float* __restrict__ resin, // residual source  [B,N,D]
                 float* __restrict__ resout,      // output           [B,N,D]
                 const float* __restrict__ ln_g, const float* __restrict__ ln_b,
                 const float* __restrict__ qkvw, const float* __restrict__ qkvb,
                 const float* __restrict__ ow,   const float* __restrict__ ob)
{
    __shared__ float xs[16][132];     // LN'd window tokens
    __shared__ float qkvs[16][392];   // q(0:128) k(128:256) v(256:384)
    __shared__ float sc[2][16][16];   // attention probs
    __shared__ float os[16][132];     // attn output pre-proj
    __shared__ int   nmap[16];

    const int t = threadIdx.x;
    const int p = t >> 4;     // token in window 0..15
    const int l = t & 15;     // 16 lanes per token
    const int b  = blockIdx.x >> 10;
    const int iw = blockIdx.x & 1023;

    // image position of (iw, p) in the (possibly rolled) image
    int r = ((iw >> 5) << 2) | (p >> 2);
    int c = ((iw & 31) << 2) | (p & 3);
    int nsrc;
    if (BRANCH == 1) {
        nsrc = (r << 7) | c;                         // image-order flat index
    } else {
        int r2 = (r + 2) & 127, c2 = (c + 2) & 127;  // undo roll(-2,-2)
        nsrc = ((((r2 >> 2) << 5) | (c2 >> 2)) << 4) | ((r2 & 3) << 2) | (c2 & 3);
    }
    if (l == 0) nmap[p] = nsrc;

    // ---- LayerNorm (16 lanes per token, 8 dims each) ----
    {
        const float* src = xin + ((size_t)b * NTOK + nsrc) * DD + l * 8;
        float v0[8];
        *(float4*)&v0[0] = *(const float4*)&src[0];
        *(float4*)&v0[4] = *(const float4*)&src[4];
        float s = 0.f, s2 = 0.f;
#pragma unroll
        for (int i = 0; i < 8; ++i) { s += v0[i]; s2 += v0[i] * v0[i]; }
#pragma unroll
        for (int m = 8; m >= 1; m >>= 1) {
            s  += __shfl_xor(s,  m, 16);
            s2 += __shfl_xor(s2, m, 16);
        }
        float mu   = s * (1.f / 128.f);
        float var  = s2 * (1.f / 128.f) - mu * mu;
        float rstd = rsqrtf(var + 1e-5f);
#pragma unroll
        for (int i = 0; i < 8; ++i) {
            int d = l * 8 + i;
            xs[p][d] = (v0[i] - mu) * rstd * ln_g[d] + ln_b[d];
        }
    }
    __syncthreads();

    // ---- QKV: qkvs[p][j] = dot(xs[p], Wqkv[j]) + b[j] ----
    for (int part = 0; part < 3; ++part) {
        const int jbase = part * 128 + l * 8;
        float acc[8];
#pragma unroll
        for (int jj = 0; jj < 8; ++jj) acc[jj] = qkvb[jbase + jj];
        for (int k = 0; k < 128; k += 4) {
            float4 xv = *(const float4*)&xs[p][k];
#pragma unroll
            for (int jj = 0; jj < 8; ++jj) {
                float4 wv = *(const float4*)&qkvw[(size_t)(jbase + jj) * 128 + k];
                acc[jj] = fmaf(xv.x, wv.x, fmaf(xv.y, wv.y, fmaf(xv.z, wv.z, fmaf(xv.w, wv.w, acc[jj]))));
            }
        }
#pragma unroll
        for (int jj = 0; jj < 8; ++jj) qkvs[p][jbase + jj] = acc[jj];
    }
    __syncthreads();

    // ---- scores: 512 of them (2 heads x 16 x 16), 2 per thread ----
    for (int idx = t; idx < 512; idx += 256) {
        int h = idx >> 8, rem = idx & 255;
        int qi = rem >> 4, ki = rem & 15;
        const float* qp = &qkvs[qi][h * 64];
        const float* kp = &qkvs[ki][128 + h * 64];
        float acc = 0.f;
#pragma unroll
        for (int d = 0; d < 64; ++d) acc = fmaf(qp[d], kp[d], acc);
        sc[h][qi][ki] = acc * 0.125f;   // 1/sqrt(64)
    }
    __syncthreads();

    // ---- softmax over k (32 rows, one thread each) ----
    if (t < 32) {
        int h = t >> 4, qi = t & 15;
        float* row = sc[h][qi];
        float m = row[0];
#pragma unroll
        for (int i = 1; i < 16; ++i) m = fmaxf(m, row[i]);
        float sum = 0.f;
#pragma unroll
        for (int i = 0; i < 16; ++i) { float e = __expf(row[i] - m); row[i] = e; sum += e; }
        float inv = 1.f / sum;
#pragma unroll
        for (int i = 0; i < 16; ++i) row[i] *= inv;
    }
    __syncthreads();

    // ---- PV: os[p][c] = sum_ki sc[h][p][ki] * v[ki][c] ----
    {
        const int cbase = l * 8;          // stays within one head (64-aligned blocks)
        const int h = cbase >> 6;
        float acc[8] = {0, 0, 0, 0, 0, 0, 0, 0};
#pragma unroll
        for (int ki = 0; ki < 16; ++ki) {
            float sv = sc[h][p][ki];
            const float* vp = &qkvs[ki][256 + cbase];
#pragma unroll
            for (int jj = 0; jj < 8; ++jj) acc[jj] = fmaf(sv, vp[jj], acc[jj]);
        }
#pragma unroll
        for (int jj = 0; jj < 8; ++jj) os[p][cbase + jj] = acc[jj];
    }
    __syncthreads();

    // ---- output projection + residual epilogue ----
    {
        const int jbase = l * 8;
        float acc[8];
#pragma unroll
        for (int jj = 0; jj < 8; ++jj) acc[jj] = ob[jbase + jj];
        for (int k = 0; k < 128; k += 4) {
            float4 xv = *(const float4*)&os[p][k];
#pragma unroll
            for (int jj = 0; jj < 8; ++jj) {
                float4 wv = *(const float4*)&ow[(size_t)(jbase + jj) * 128 + k];
                acc[jj] = fmaf(xv.x, wv.x, fmaf(xv.y, wv.y, fmaf(xv.z, wv.z, fmaf(xv.w, wv.w, acc[jj]))));
            }
        }
        const int ndst = (BRANCH == 1) ? (iw * 16 + p) : nmap[p];
        const float* rsrc = resin + ((size_t)b * NTOK + ndst) * DD + jbase;
        float* dst = resout + ((size_t)b * NTOK + ndst) * DD + jbase;
        float out[8];
#pragma unroll
        for (int jj = 0; jj < 8; ++jj) {
            float rv = rsrc[jj];
            if (BRANCH == 1) rv = truncf(rv);
            out[jj] = rv + acc[jj];
        }
        *(float4*)&dst[0] = *(const float4*)&out[0];
        *(float4*)&dst[4] = *(const float4*)&out[4];
    }
}

// ---------------------------------------------------------------------------
// Fused MLP: out = GELU(GELU(LN(x) @ W1^T + b1) @ W2^T + b2) + x, IN-PLACE.
// One block per 16 tokens.
// ---------------------------------------------------------------------------
__global__ __launch_bounds__(256, 2)
void mlp_kernel(float* __restrict__ buf,
                const float* __restrict__ ln_g, const float* __restrict__ ln_b,
                const float* __restrict__ w1, const float* __restrict__ b1,
                const float* __restrict__ w2, const float* __restrict__ b2)
{
    __shared__ float xt[16][132];
    __shared__ float h1s[16][516];

    const int t = threadIdx.x;
    const int p = t >> 4;
    const int l = t & 15;
    const size_t n = (size_t)blockIdx.x * 16 + p;

    float v0[8];  // residual values for dims [l*8, l*8+8) — reused in epilogue
    {
        const float* src = buf + n * DD + l * 8;
        *(float4*)&v0[0] = *(const float4*)&src[0];
        *(float4*)&v0[4] = *(const float4*)&src[4];
        float s = 0.f, s2 = 0.f;
#pragma unroll
        for (int i = 0; i < 8; ++i) { s += v0[i]; s2 += v0[i] * v0[i]; }
#pragma unroll
        for (int m = 8; m >= 1; m >>= 1) {
            s  += __shfl_xor(s,  m, 16);
            s2 += __shfl_xor(s2, m, 16);
        }
        float mu   = s * (1.f / 128.f);
        float var  = s2 * (1.f / 128.f) - mu * mu;
        float rstd = rsqrtf(var + 1e-5f);
#pragma unroll
        for (int i = 0; i < 8; ++i) {
            int d = l * 8 + i;
            xt[p][d] = (v0[i] - mu) * rstd * ln_g[d] + ln_b[d];
        }
    }
    __syncthreads();

    // h1[j] = GELU(dot(xt[p], w1[j]) + b1[j]), j in [l*32, l*32+32), 2 chunks
    for (int ch = 0; ch < 2; ++ch) {
        const int jbase = l * 32 + ch * 16;
        float acc[16];
#pragma unroll
        for (int jj = 0; jj < 16; ++jj) acc[jj] = b1[jbase + jj];
        for (int k = 0; k < 128; k += 4) {
            float4 xv = *(const float4*)&xt[p][k];
#pragma unroll
            for (int jj = 0; jj < 16; ++jj) {
                float4 wv = *(const float4*)&w1[(size_t)(jbase + jj) * 128 + k];
                acc[jj] = fmaf(xv.x, wv.x, fmaf(xv.y, wv.y, fmaf(xv.z, wv.z, fmaf(xv.w, wv.w, acc[jj]))));
            }
        }
#pragma unroll
        for (int jj = 0; jj < 16; ++jj) h1s[p][jbase + jj] = gelu_exact(acc[jj]);
    }
    __syncthreads();

    // h2[j] = GELU(dot(h1, w2[j]) + b2[j]) + residual, j in [l*8, l*8+8)
    {
        const int jbase = l * 8;
        float acc[8];
#pragma unroll
        for (int jj = 0; jj < 8; ++jj) acc[jj] = b2[jbase + jj];
        for (int k = 0; k < 512; k += 4) {
            float4 hv = *(const float4*)&h1s[p][k];
#pragma unroll
            for (int jj = 0; jj < 8; ++jj) {
                float4 wv = *(const float4*)&w2[(size_t)(jbase + jj) * 512 + k];
                acc[jj] = fmaf(hv.x, wv.x, fmaf(hv.y, wv.y, fmaf(hv.z, wv.z, fmaf(hv.w, wv.w, acc[jj]))));
            }
        }
        float* dst = buf + n * DD + jbase;
        float out[8];
#pragma unroll
        for (int jj = 0; jj < 8; ++jj) out[jj] = gelu_exact(acc[jj]) + v0[jj];
        *(float4*)&dst[0] = *(const float4*)&out[0];
        *(float4*)&dst[4] = *(const float4*)&out[4];
    }
}

extern "C" void kernel_launch(void* const* d_in, const int* in_sizes, int n_in,
                              void* d_out, int out_size, void* d_ws, size_t ws_size,
                              hipStream_t stream) {
    (void)in_sizes; (void)n_in; (void)out_size; (void)ws_size;
    const float* x      = (const float*)d_in[0];
    const float* ln1_g  = (const float*)d_in[1];
    const float* ln1_b  = (const float*)d_in[2];
    const float* ln2_g  = (const float*)d_in[3];
    const float* ln2_b  = (const float*)d_in[4];
    const float* ln3_g  = (const float*)d_in[5];
    const float* ln3_b  = (const float*)d_in[6];
    const float* ln4_g  = (const float*)d_in[7];
    const float* ln4_b  = (const float*)d_in[8];
    const float* qkv1_w = (const float*)d_in[9];
    const float* qkv1_b = (const float*)d_in[10];
    const float* out1_w = (const float*)d_in[11];
    const float* out1_b = (const float*)d_in[12];
    const float* qkv2_w = (const float*)d_in[13];
    const float* qkv2_b = (const float*)d_in[14];
    const float* out2_w = (const float*)d_in[15];
    const float* out2_b = (const float*)d_in[16];
    const float* mlp1_w1 = (const float*)d_in[17];
    const float* mlp1_b1 = (const float*)d_in[18];
    const float* mlp1_w2 = (const float*)d_in[19];
    const float* mlp1_b2 = (const float*)d_in[20];
    const float* mlp2_w1 = (const float*)d_in[21];
    const float* mlp2_b1 = (const float*)d_in[22];
    const float* mlp2_w2 = (const float*)d_in[23];
    const float* mlp2_b2 = (const float*)d_in[24];

    float* ws0 = (float*)d_ws;        // res1 -> out1 (in-place), 64 MiB
    float* out = (float*)d_out;       // res2 -> out2 (in-place)

    const int nblk = 8 * 1024;        // B * nW  (== B*N/16 for MLP)
    dim3 blk(256);

    // 1) W-MSA: res1 = trunc(x) + a1           (ws0)
    attn_kernel<1><<<nblk, blk, 0, stream>>>(x, x, ws0,
        ln1_g, ln1_b, qkv1_w, qkv1_b, out1_w, out1_b);
    // 2) MLP1: out1 = GELU-MLP(LN2(res1)) + res1   (in-place ws0)
    mlp_kernel<<<nblk, blk, 0, stream>>>(ws0, ln2_g, ln2_b,
        mlp1_w1, mlp1_b1, mlp1_w2, mlp1_b2);
    // 3) SW-MSA: res2 = out1 + a2(roll-mapped)     (d_out)
    attn_kernel<2><<<nblk, blk, 0, stream>>>(ws0, ws0, out,
        ln3_g, ln3_b, qkv2_w, qkv2_b, out2_w, out2_b);
    // 4) MLP2: out2 = GELU-MLP(LN4(res2)) + res2   (in-place d_out)
    mlp_kernel<<<nblk, blk, 0, stream>>>(out, ln4_g, ln4_b,
        mlp2_w1, mlp2_b1, mlp2_w2, mlp2_b2);
}

// Round 2
// 573.767 us; speedup vs baseline: 37.0934x; 37.0934x over previous
//
#include <hip/hip_runtime.h>

// B=8, N=16384 (H=W=128), D=128, WS=4 -> nW=1024, P=16 tokens/window, NH=2, dh=64.
// All GEMMs via v_mfma_f32_16x16x32_bf16 (inputs bf16, accum fp32).

typedef unsigned short u16;
typedef unsigned int   u32;
typedef __attribute__((ext_vector_type(8))) short bf16x8;
typedef __attribute__((ext_vector_type(4))) float f32x4;

#define MFMA(a,b,c) __builtin_amdgcn_mfma_f32_16x16x32_bf16(a,b,c,0,0,0)

__device__ __forceinline__ u16 f2bf(float x) {           // RNE fp32->bf16
    u32 u = __float_as_uint(x);
    return (u16)((u + 0x7FFFu + ((u >> 16) & 1u)) >> 16);
}
__device__ __forceinline__ float gelu_exact(float x) {
    return 0.5f * x * (1.0f + erff(x * 0.7071067811865475f));
}
// load 8 consecutive fp32 from global, convert to bf16x8 fragment
__device__ __forceinline__ bf16x8 ldb8(const float* __restrict__ p) {
    float4 a = *(const float4*)p;
    float4 b = *(const float4*)(p + 4);
    bf16x8 r;
    r[0]=(short)f2bf(a.x); r[1]=(short)f2bf(a.y); r[2]=(short)f2bf(a.z); r[3]=(short)f2bf(a.w);
    r[4]=(short)f2bf(b.x); r[5]=(short)f2bf(b.y); r[6]=(short)f2bf(b.z); r[7]=(short)f2bf(b.w);
    return r;
}
__device__ __forceinline__ bf16x8 ldsfrag(const u16* base, int byte) {
    return *(const bf16x8*)((const char*)base + byte);
}
// image/window index plumbing. wg = window-group (8 windows), tok in [0,128).
// branch 1: image-order flat index; branch 2: roll(-2,-2)-mapped window-order index.
template <int BRANCH>
__device__ __forceinline__ int src_index(int wg, int tok) {
    int win = (wg << 3) + (tok >> 4), p = tok & 15;
    int r = ((win >> 5) << 2) | (p >> 2);
    int c = ((win & 31) << 2) | (p & 3);
    if (BRANCH == 1) return (r << 7) | c;
    int r2 = (r + 2) & 127, c2 = (c + 2) & 127;
    return ((((r2 >> 2) << 5) | (c2 >> 2)) << 4) | ((r2 & 3) << 2) | (c2 & 3);
}

// ---------------------------------------------------------------------------
// Fused windowed MHSA. 1 block = 8 windows = 128 tokens. 512 threads (8 waves).
// LDS: xs 32K (LN'd x, later attn-out), q 32K (later P), k 32K, vt 48K = 144K.
// ---------------------------------------------------------------------------
template <int BRANCH>
__global__ __launch_bounds__(512, 2)
void attn_mfma(const float* __restrict__ xin, const float* __restrict__ resin,
               float* __restrict__ resout,
               const float* __restrict__ ln_g, const float* __restrict__ ln_b,
               const float* __restrict__ qkvw, const float* __restrict__ qkvb,
               const float* __restrict__ ow,   const float* __restrict__ ob)
{
    __shared__ __align__(16) u16 xs [128 * 128];   // stride 256 B, XOR-swizzled
    __shared__ __align__(16) u16 qls[128 * 128];   // stride 256 B
    __shared__ __align__(16) u16 kls[128 * 128];   // stride 256 B
    __shared__ __align__(16) u16 vt [128 * 192];   // [dh][token], stride 384 B (3*128 -> no XOR escape)

    const int t  = threadIdx.x;
    const int wv = t >> 6, ln = t & 63, l15 = ln & 15, q4 = ln >> 4;
    const int bb = blockIdx.x >> 7, wg = blockIdx.x & 127;
    const int xa = (l15 & 7) << 4;                 // XOR for rows == l15 (mod 8)

    // ---------- phase 0: gather + LayerNorm -> xs (bf16); zero vt pad ----------
    {
        int token = t >> 2, part = t & 3;
        int nsrc = src_index<BRANCH>(wg, token);
        const float* src = xin + ((size_t)bb * 16384 + nsrc) * 128 + part * 32;
        float v[32];
#pragma unroll
        for (int i = 0; i < 8; ++i) *(float4*)&v[i * 4] = ((const float4*)src)[i];
        float s = 0.f, s2 = 0.f;
#pragma unroll
        for (int i = 0; i < 32; ++i) { s += v[i]; s2 += v[i] * v[i]; }
        s  += __shfl_xor(s, 1, 4);  s  += __shfl_xor(s, 2, 4);
        s2 += __shfl_xor(s2, 1, 4); s2 += __shfl_xor(s2, 2, 4);
        float mu = s * (1.f / 128.f);
        float rstd = rsqrtf(s2 * (1.f / 128.f) - mu * mu + 1e-5f);
        int tx = (token & 7) << 4;
#pragma unroll
        for (int g = 0; g < 4; ++g) {
            uint4 u; u32* up = (u32*)&u;
#pragma unroll
            for (int j = 0; j < 4; ++j) {
                int d0 = part * 32 + g * 8 + j * 2;
                float a = (v[g * 8 + j * 2]     - mu) * rstd * ln_g[d0]     + ln_b[d0];
                float c = (v[g * 8 + j * 2 + 1] - mu) * rstd * ln_g[d0 + 1] + ln_b[d0 + 1];
                up[j] = (u32)f2bf(a) | ((u32)f2bf(c) << 16);
            }
            int byte = token * 256 + ((part * 64 + g * 16) ^ tx);
            *(uint4*)((char*)xs + byte) = u;
        }
        // zero vt token-slots [128,192) (read for window 7's K>=16 pad lanes)
        int row = t >> 2, g2 = t & 3;
        uint4 z = {0, 0, 0, 0};
#pragma unroll
        for (int i = 0; i < 2; ++i) {
            int byte = row * 384 + ((256 + g2 * 32 + i * 16) ^ ((row & 7) << 4));
            *(uint4*)((char*)vt + byte) = z;
        }
    }
    __syncthreads();

    // ---------- phase 1: QKV GEMM (M=128,N=384,K=128). wave owns 3 n-frags ----------
#pragma unroll
    for (int i = 0; i < 3; ++i) {
        int n0 = (wv * 3 + i) * 16;
        int part = n0 >> 7, c0 = n0 & 127;
        float bias = qkvb[n0 + l15];
        f32x4 acc[8];
#pragma unroll
        for (int mf = 0; mf < 8; ++mf) acc[mf] = (f32x4){bias, bias, bias, bias};
#pragma unroll
        for (int kf = 0; kf < 4; ++kf) {
            bf16x8 bfr = ldb8(qkvw + (size_t)(n0 + l15) * 128 + kf * 32 + q4 * 8);
#pragma unroll
            for (int mf = 0; mf < 8; ++mf) {
                bf16x8 afr = ldsfrag(xs, (mf * 16 + l15) * 256 + ((kf * 64 + q4 * 16) ^ xa));
                acc[mf] = MFMA(afr, bfr, acc[mf]);
            }
        }
        if (part < 2) {                       // q (scaled 1/sqrt(64)) or k, token-major
            u16* dst = part ? kls : qls;
            float sc = part ? 1.f : 0.125f;
#pragma unroll
            for (int mf = 0; mf < 8; ++mf)
#pragma unroll
                for (int r = 0; r < 4; ++r) {
                    int tok = mf * 16 + q4 * 4 + r;
                    int byte = tok * 256 + ((2 * (c0 + l15)) ^ ((tok & 7) << 4));
                    dst[byte >> 1] = f2bf(acc[mf][r] * sc);
                }
        } else {                              // v -> vt[dh][token], 4 tokens packed per 8B
            int dh = c0 + l15, xr = (dh & 7) << 4;
#pragma unroll
            for (int mf = 0; mf < 8; ++mf) {
                int tok0 = mf * 16 + q4 * 4;
                u32 lo = (u32)f2bf(acc[mf][0]) | ((u32)f2bf(acc[mf][1]) << 16);
                u32 hi = (u32)f2bf(acc[mf][2]) | ((u32)f2bf(acc[mf][3]) << 16);
                int byte = dh * 384 + ((2 * tok0) ^ xr);
                *(uint2*)((char*)vt + byte) = make_uint2(lo, hi);
            }
        }
    }
    __syncthreads();

    // ---------- phase 2: scores (2 per wave): S = mfma(Q, K^T) over dh=64 ----------
    f32x4 S[2];
#pragma unroll
    for (int s = 0; s < 2; ++s) {
        int pair = wv * 2 + s, win = pair >> 1, h = pair & 1;
        f32x4 z = {0.f, 0.f, 0.f, 0.f};
        int tok = win * 16 + l15;
#pragma unroll
        for (int kf = 0; kf < 2; ++kf) {
            int byte = tok * 256 + ((h * 128 + kf * 64 + q4 * 16) ^ xa);
            bf16x8 aq = ldsfrag(qls, byte);
            bf16x8 bk = ldsfrag(kls, byte);
            z = MFMA(aq, bk, z);
        }
        S[s] = z;
    }
    __syncthreads();   // all q reads done before P overlays qls

    // ---------- softmax in-register, write P (bf16, K padded to 32 with zeros) ----------
#pragma unroll
    for (int s = 0; s < 2; ++s) {
        int pair = wv * 2 + s, win = pair >> 1, h = pair & 1;
#pragma unroll
        for (int r = 0; r < 4; ++r) {
            float v = S[s][r];
            float m = v;
            m = fmaxf(m, __shfl_xor(m, 1, 16)); m = fmaxf(m, __shfl_xor(m, 2, 16));
            m = fmaxf(m, __shfl_xor(m, 4, 16)); m = fmaxf(m, __shfl_xor(m, 8, 16));
            float e = __expf(v - m);
            float sm = e;
            sm += __shfl_xor(sm, 1, 16); sm += __shfl_xor(sm, 2, 16);
            sm += __shfl_xor(sm, 4, 16); sm += __shfl_xor(sm, 8, 16);
            float p = e / sm;
            int tok = win * 16 + q4 * 4 + r, tx = (tok & 7) << 4;
            qls[(tok * 128 + ((h * 64 + l15 * 2)      ^ tx)) >> 1] = f2bf(p);
            qls[(tok * 128 + ((h * 64 + 32 + l15 * 2) ^ tx)) >> 1] = 0;   // K pad
        }
    }
    __syncthreads();

    // ---------- phase 3: PV (K=32: 16 real keys + 16 zero-pad) -> os (= xs) ----------
#pragma unroll
    for (int s = 0; s < 2; ++s) {
        int pair = wv * 2 + s, win = pair >> 1, h = pair & 1;
        bf16x8 ap = ldsfrag(qls, (win * 16 + l15) * 128 + ((h * 64 + q4 * 16) ^ xa));
#pragma unroll
        for (int nf = 0; nf < 4; ++nf) {
            int dh = h * 64 + nf * 16 + l15;
            bf16x8 bv = ldsfrag(vt, dh * 384 + ((win * 32 + q4 * 16) ^ xa));
            f32x4 z = {0.f, 0.f, 0.f, 0.f};
            f32x4 o = MFMA(ap, bv, z);
#pragma unroll
            for (int r = 0; r < 4; ++r) {
                int tok = win * 16 + q4 * 4 + r;
                xs[(tok * 256 + ((2 * dh) ^ ((tok & 7) << 4))) >> 1] = f2bf(o[r]);
            }
        }
    }
    __syncthreads();

    // ---------- phase 4: output projection + residual epilogue ----------
    {
        int n0 = wv * 16;
        float bias = ob[n0 + l15];
        f32x4 acc[8];
#pragma unroll
        for (int mf = 0; mf < 8; ++mf) acc[mf] = (f32x4){bias, bias, bias, bias};
#pragma unroll
        for (int kf = 0; kf < 4; ++kf) {
            bf16x8 bfr = ldb8(ow + (size_t)(n0 + l15) * 128 + kf * 32 + q4 * 8);
#pragma unroll
            for (int mf = 0; mf < 8; ++mf) {
                bf16x8 afr = ldsfrag(xs, (mf * 16 + l15) * 256 + ((kf * 64 + q4 * 16) ^ xa));
                acc[mf] = MFMA(afr, bfr, acc[mf]);
            }
        }
#pragma unroll
        for (int mf = 0; mf < 8; ++mf)
#pragma unroll
            for (int r = 0; r < 4; ++r) {
                int tok = mf * 16 + q4 * 4 + r;
                int nd = (BRANCH == 1) ? (wg * 128 + tok) : src_index<2>(wg, tok);
                size_t ridx = ((size_t)bb * 16384 + nd) * 128 + n0 + l15;
                float rv = resin[ridx];
                if (BRANCH == 1) rv = truncf(rv);
                resout[ridx] = rv + acc[mf][r];
            }
    }
}

// ---------------------------------------------------------------------------
// Fused MLP (in place): buf = GELU(GELU(LN(buf)@W1^T+b1)@W2^T+b2) + buf.
// 1 block = 64 tokens, 256 threads (4 waves). LDS: xs 16K + h1 64K = 80K.
// ---------------------------------------------------------------------------
__global__ __launch_bounds__(256, 2)
void mlp_mfma(float* __restrict__ buf,
              const float* __restrict__ ln_g, const float* __restrict__ ln_b,
              const float* __restrict__ w1, const float* __restrict__ b1,
              const float* __restrict__ w2, const float* __restrict__ b2)
{
    __shared__ __align__(16) u16 xs[64 * 128];    // stride 256 B
    __shared__ __align__(16) u16 h1[64 * 512];    // stride 1024 B

    const int t = threadIdx.x;
    const int wv = t >> 6, ln = t & 63, l15 = ln & 15, q4 = ln >> 4;
    const int xa = (l15 & 7) << 4;
    const size_t base = (size_t)blockIdx.x * 64 * 128;

    // ---------- LN -> xs (bf16) ----------
    {
        int token = t >> 2, part = t & 3;
        const float* src = buf + base + token * 128 + part * 32;
        float v[32];
#pragma unroll
        for (int i = 0; i < 8; ++i) *(float4*)&v[i * 4] = ((const float4*)src)[i];
        float s = 0.f, s2 = 0.f;
#pragma unroll
        for (int i = 0; i < 32; ++i) { s += v[i]; s2 += v[i] * v[i]; }
        s  += __shfl_xor(s, 1, 4);  s  += __shfl_xor(s, 2, 4);
        s2 += __shfl_xor(s2, 1, 4); s2 += __shfl_xor(s2, 2, 4);
        float mu = s * (1.f / 128.f);
        float rstd = rsqrtf(s2 * (1.f / 128.f) - mu * mu + 1e-5f);
        int tx = (token & 7) << 4;
#pragma unroll
        for (int g = 0; g < 4; ++g) {
            uint4 u; u32* up = (u32*)&u;
#pragma unroll
            for (int j = 0; j < 4; ++j) {
                int d0 = part * 32 + g * 8 + j * 2;
                float a = (v[g * 8 + j * 2]     - mu) * rstd * ln_g[d0]     + ln_b[d0];
                float c = (v[g * 8 + j * 2 + 1] - mu) * rstd * ln_g[d0 + 1] + ln_b[d0 + 1];
                up[j] = (u32)f2bf(a) | ((u32)f2bf(c) << 16);
            }
            int byte = token * 256 + ((part * 64 + g * 16) ^ tx);
            *(uint4*)((char*)xs + byte) = u;
        }
    }
    __syncthreads();

    // ---------- GEMM1: h1 = GELU(xs @ W1^T + b1). wave owns N-slice of 128 ----------
    {
        const int nb = wv * 128;
        f32x4 acc[4][8];
#pragma unroll
        for (int nf = 0; nf < 8; ++nf) {
            float bias = b1[nb + nf * 16 + l15];
#pragma unroll
            for (int mf = 0; mf < 4; ++mf) acc[mf][nf] = (f32x4){bias, bias, bias, bias};
        }
#pragma unroll
        for (int kf = 0; kf < 4; ++kf) {
            bf16x8 a[4];
#pragma unroll
            for (int mf = 0; mf < 4; ++mf)
                a[mf] = ldsfrag(xs, (mf * 16 + l15) * 256 + ((kf * 64 + q4 * 16) ^ xa));
#pragma unroll
            for (int nf = 0; nf < 8; ++nf) {
                bf16x8 bfr = ldb8(w1 + (size_t)(nb + nf * 16 + l15) * 128 + kf * 32 + q4 * 8);
#pragma unroll
                for (int mf = 0; mf < 4; ++mf) acc[mf][nf] = MFMA(a[mf], bfr, acc[mf][nf]);
            }
        }
#pragma unroll
        for (int nf = 0; nf < 8; ++nf) {
            int col = nb + nf * 16 + l15;
#pragma unroll
            for (int mf = 0; mf < 4; ++mf)
#pragma unroll
                for (int r = 0; r < 4; ++r) {
                    int tok = mf * 16 + q4 * 4 + r;
                    int byte = tok * 1024 + ((2 * col) ^ ((tok & 7) << 4));
                    h1[byte >> 1] = f2bf(gelu_exact(acc[mf][nf][r]));
                }
        }
    }
    __syncthreads();

    // ---------- GEMM2: out = GELU(h1 @ W2^T + b2) + residual. wave owns 32 cols ----------
    {
        const int nb = wv * 32;
        f32x4 acc[4][2];
#pragma unroll
        for (int nf = 0; nf < 2; ++nf) {
            float bias = b2[nb + nf * 16 + l15];
#pragma unroll
            for (int mf = 0; mf < 4; ++mf) acc[mf][nf] = (f32x4){bias, bias, bias, bias};
        }
#pragma unroll
        for (int kf = 0; kf < 16; ++kf) {
            bf16x8 a[4];
#pragma unroll
            for (int mf = 0; mf < 4; ++mf)
                a[mf] = ldsfrag(h1, (mf * 16 + l15) * 1024 + ((kf * 64 + q4 * 16) ^ xa));
#pragma unroll
            for (int nf = 0; nf < 2; ++nf) {
                bf16x8 bfr = ldb8(w2 + (size_t)(nb + nf * 16 + l15) * 512 + kf * 32 + q4 * 8);
#pragma unroll
                for (int mf = 0; mf < 4; ++mf) acc[mf][nf] = MFMA(a[mf], bfr, acc[mf][nf]);
            }
        }
#pragma unroll
        for (int nf = 0; nf < 2; ++nf) {
            int col = nb + nf * 16 + l15;
#pragma unroll
            for (int mf = 0; mf < 4; ++mf)
#pragma unroll
                for (int r = 0; r < 4; ++r) {
                    int tok = mf * 16 + q4 * 4 + r;
                    size_t idx = base + (size_t)tok * 128 + col;
                    float rv = buf[idx];
                    buf[idx] = gelu_exact(acc[mf][nf][r]) + rv;
                }
        }
    }
}

extern "C" void kernel_launch(void* const* d_in, const int* in_sizes, int n_in,
                              void* d_out, int out_size, void* d_ws, size_t ws_size,
                              hipStream_t stream) {
    (void)in_sizes; (void)n_in; (void)out_size; (void)ws_size;
    const float* x      = (const float*)d_in[0];
    const float* ln1_g  = (const float*)d_in[1];
    const float* ln1_b  = (const float*)d_in[2];
    const float* ln2_g  = (const float*)d_in[3];
    const float* ln2_b  = (const float*)d_in[4];
    const float* ln3_g  = (const float*)d_in[5];
    const float* ln3_b  = (const float*)d_in[6];
    const float* ln4_g  = (const float*)d_in[7];
    const float* ln4_b  = (const float*)d_in[8];
    const float* qkv1_w = (const float*)d_in[9];
    const float* qkv1_b = (const float*)d_in[10];
    const float* out1_w = (const float*)d_in[11];
    const float* out1_b = (const float*)d_in[12];
    const float* qkv2_w = (const float*)d_in[13];
    const float* qkv2_b = (const float*)d_in[14];
    const float* out2_w = (const float*)d_in[15];
    const float* out2_b = (const float*)d_in[16];
    const float* mlp1_w1 = (const float*)d_in[17];
    const float* mlp1_b1 = (const float*)d_in[18];
    const float* mlp1_w2 = (const float*)d_in[19];
    const float* mlp1_b2 = (const float*)d_in[20];
    const float* mlp2_w1 = (const float*)d_in[21];
    const float* mlp2_b1 = (const float*)d_in[22];
    const float* mlp2_w2 = (const float*)d_in[23];
    const float* mlp2_b2 = (const float*)d_in[24];

    float* ws0 = (float*)d_ws;     // res1 -> out1 (in place), 64 MiB
    float* out = (float*)d_out;    // res2 -> out2 (in place)

    // 1) W-MSA: res1 = trunc(x) + a1
    attn_mfma<1><<<dim3(1024), dim3(512), 0, stream>>>(x, x, ws0,
        ln1_g, ln1_b, qkv1_w, qkv1_b, out1_w, out1_b);
    // 2) MLP1 (in place on ws0)
    mlp_mfma<<<dim3(2048), dim3(256), 0, stream>>>(ws0, ln2_g, ln2_b,
        mlp1_w1, mlp1_b1, mlp1_w2, mlp1_b2);
    // 3) SW-MSA: res2 = out1 + a2 (roll-mapped gather == scatter)
    attn_mfma<2><<<dim3(1024), dim3(512), 0, stream>>>(ws0, ws0, out,
        ln3_g, ln3_b, qkv2_w, qkv2_b, out2_w, out2_b);
    // 4) MLP2 (in place on d_out)
    mlp_mfma<<<dim3(2048), dim3(256), 0, stream>>>(out, ln4_g, ln4_b,
        mlp2_w1, mlp2_b1, mlp2_w2, mlp2_b2);
}

// Round 3
// 468.462 us; speedup vs baseline: 45.4315x; 1.2248x over previous
//
#include <hip/hip_runtime.h>

// B=8, N=16384 (H=W=128), D=128, WS=4 -> nW=1024, P=16 tokens/window, NH=2, dh=64.
// All GEMMs via v_mfma_f32_16x16x32_bf16. Weights pre-converted to bf16 in d_ws.
// Activations live in d_out and are updated in place stage by stage.

typedef unsigned short u16;
typedef unsigned int   u32;
typedef __attribute__((ext_vector_type(8))) short bf16x8;
typedef __attribute__((ext_vector_type(4))) float f32x4;

#define MFMA(a,b,c) __builtin_amdgcn_mfma_f32_16x16x32_bf16(a,b,c,0,0,0)

__device__ __forceinline__ u16 f2bf(float x) {           // RNE fp32->bf16
    u32 u = __float_as_uint(x);
    return (u16)((u + 0x7FFFu + ((u >> 16) & 1u)) >> 16);
}
__device__ __forceinline__ u32 pack2(float lo, float hi) {
    return (u32)f2bf(lo) | ((u32)f2bf(hi) << 16);
}
// tanh-form GELU via hw exp2 + rcp (~8 VALU ops). |err| vs exact erf-GELU < ~1e-3.
__device__ __forceinline__ float gelu_fast(float x) {
    float t = x * fmaf(x * x, 0.044715f, 1.0f);
    float e = __builtin_amdgcn_exp2f(-2.3022078f * t);   // exp(-1.5957691*t)
    return x * __builtin_amdgcn_rcpf(1.0f + e);
}
__device__ __forceinline__ bf16x8 ldsfrag(const u16* base, int byte) {
    return *(const bf16x8*)((const char*)base + byte);
}
__device__ __forceinline__ bf16x8 ldg8(const u16* __restrict__ p) {
    return *(const bf16x8*)p;
}
// branch 1: image-order flat index; branch 2: roll(-2,-2)-mapped window-order index.
template <int BRANCH>
__device__ __forceinline__ int src_index(int wg, int tok) {
    int win = (wg << 3) + (tok >> 4), p = tok & 15;
    int r = ((win >> 5) << 2) | (p >> 2);
    int c = ((win & 31) << 2) | (p & 3);
    if (BRANCH == 1) return (r << 7) | c;
    int r2 = (r + 2) & 127, c2 = (c + 2) & 127;
    return ((((r2 >> 2) << 5) | (c2 >> 2)) << 4) | ((r2 & 3) << 2) | (c2 & 3);
}

// ---------------------------------------------------------------------------
// Weight fp32 -> bf16 prep. 393216 elements total, 8 segments, 8 elems/thread.
// ---------------------------------------------------------------------------
__global__ __launch_bounds__(256)
void cvt_weights(const float* __restrict__ qkv1, const float* __restrict__ o1,
                 const float* __restrict__ w11,  const float* __restrict__ w12,
                 const float* __restrict__ qkv2, const float* __restrict__ o2,
                 const float* __restrict__ w21,  const float* __restrict__ w22,
                 u16* __restrict__ dst)
{
    int e = (blockIdx.x * 256 + threadIdx.x) * 8;
    const float* src; int off;
    if      (e < 49152)  { src = qkv1; off = 0; }
    else if (e < 65536)  { src = o1;   off = 49152; }
    else if (e < 131072) { src = w11;  off = 65536; }
    else if (e < 196608) { src = w12;  off = 131072; }
    else if (e < 245760) { src = qkv2; off = 196608; }
    else if (e < 262144) { src = o2;   off = 245760; }
    else if (e < 327680) { src = w21;  off = 262144; }
    else                 { src = w22;  off = 327680; }
    float4 a = *(const float4*)(src + (e - off));
    float4 b = *(const float4*)(src + (e - off) + 4);
    uint4 o;
    o.x = pack2(a.x, a.y); o.y = pack2(a.z, a.w);
    o.z = pack2(b.x, b.y); o.w = pack2(b.z, b.w);
    *(uint4*)(dst + e) = o;
}

// ---------------------------------------------------------------------------
// Fused windowed MHSA. 1 block = 8 windows = 128 tokens. 512 threads (8 waves).
// ---------------------------------------------------------------------------
template <int BRANCH>
__global__ __launch_bounds__(512, 2)
void attn_mfma(const float* __restrict__ xin, const float* __restrict__ resin,
               float* __restrict__ resout,
               const float* __restrict__ ln_g, const float* __restrict__ ln_b,
               const u16* __restrict__ qkvw, const float* __restrict__ qkvb,
               const u16* __restrict__ ow,   const float* __restrict__ ob)
{
    __shared__ __align__(16) u16 xs [128 * 128];   // LN'd x, later attn-out (256 B stride)
    __shared__ __align__(16) u16 qls[128 * 128];   // q, later P
    __shared__ __align__(16) u16 kls[128 * 128];   // k
    __shared__ __align__(16) u16 vt [128 * 192];   // [dh][token], 384 B stride

    const int t  = threadIdx.x;
    const int wv = t >> 6, ln = t & 63, l15 = ln & 15, q4 = ln >> 4;
    const int bb = blockIdx.x >> 7, wg = blockIdx.x & 127;
    const int xa = (l15 & 7) << 4;

    // ---------- phase 0: gather + LayerNorm -> xs (bf16); zero vt pad ----------
    {
        int token = t >> 2, part = t & 3;
        int nsrc = src_index<BRANCH>(wg, token);
        const float* src = xin + ((size_t)bb * 16384 + nsrc) * 128 + part * 32;
        float v[32];
#pragma unroll
        for (int i = 0; i < 8; ++i) *(float4*)&v[i * 4] = ((const float4*)src)[i];
        float s = 0.f, s2 = 0.f;
#pragma unroll
        for (int i = 0; i < 32; ++i) { s += v[i]; s2 += v[i] * v[i]; }
        s  += __shfl_xor(s, 1, 4);  s  += __shfl_xor(s, 2, 4);
        s2 += __shfl_xor(s2, 1, 4); s2 += __shfl_xor(s2, 2, 4);
        float mu = s * (1.f / 128.f);
        float rstd = rsqrtf(s2 * (1.f / 128.f) - mu * mu + 1e-5f);
        int tx = (token & 7) << 4;
#pragma unroll
        for (int g = 0; g < 4; ++g) {
            uint4 u; u32* up = (u32*)&u;
#pragma unroll
            for (int j = 0; j < 4; ++j) {
                int d0 = part * 32 + g * 8 + j * 2;
                float a = (v[g * 8 + j * 2]     - mu) * rstd * ln_g[d0]     + ln_b[d0];
                float c = (v[g * 8 + j * 2 + 1] - mu) * rstd * ln_g[d0 + 1] + ln_b[d0 + 1];
                up[j] = (u32)f2bf(a) | ((u32)f2bf(c) << 16);
            }
            int byte = token * 256 + ((part * 64 + g * 16) ^ tx);
            *(uint4*)((char*)xs + byte) = u;
        }
        int row = t >> 2, g2 = t & 3;
        uint4 z = {0, 0, 0, 0};
#pragma unroll
        for (int i = 0; i < 2; ++i) {
            int byte = row * 384 + ((256 + g2 * 32 + i * 16) ^ ((row & 7) << 4));
            *(uint4*)((char*)vt + byte) = z;
        }
    }
    __syncthreads();

    // ---------- phase 1: QKV GEMM (M=128,N=384,K=128) ----------
#pragma unroll
    for (int i = 0; i < 3; ++i) {
        int n0 = (wv * 3 + i) * 16;
        int part = n0 >> 7, c0 = n0 & 127;
        float bias = qkvb[n0 + l15];
        f32x4 acc[8];
#pragma unroll
        for (int mf = 0; mf < 8; ++mf) acc[mf] = (f32x4){bias, bias, bias, bias};
#pragma unroll
        for (int kf = 0; kf < 4; ++kf) {
            bf16x8 bfr = ldg8(qkvw + (size_t)(n0 + l15) * 128 + kf * 32 + q4 * 8);
#pragma unroll
            for (int mf = 0; mf < 8; ++mf) {
                bf16x8 afr = ldsfrag(xs, (mf * 16 + l15) * 256 + ((kf * 64 + q4 * 16) ^ xa));
                acc[mf] = MFMA(afr, bfr, acc[mf]);
            }
        }
        if (part < 2) {                       // q (scaled) / k, token-major
            u16* dst = part ? kls : qls;
            float sc = part ? 1.f : 0.125f;
#pragma unroll
            for (int mf = 0; mf < 8; ++mf)
#pragma unroll
                for (int r = 0; r < 4; ++r) {
                    int tok = mf * 16 + q4 * 4 + r;
                    int byte = tok * 256 + ((2 * (c0 + l15)) ^ ((tok & 7) << 4));
                    dst[byte >> 1] = f2bf(acc[mf][r] * sc);
                }
        } else {                              // v -> vt[dh][token]
            int dh = c0 + l15, xr = (dh & 7) << 4;
#pragma unroll
            for (int mf = 0; mf < 8; ++mf) {
                int tok0 = mf * 16 + q4 * 4;
                u32 lo = pack2(acc[mf][0], acc[mf][1]);
                u32 hi = pack2(acc[mf][2], acc[mf][3]);
                int byte = dh * 384 + ((2 * tok0) ^ xr);
                *(uint2*)((char*)vt + byte) = make_uint2(lo, hi);
            }
        }
    }
    __syncthreads();

    // ---------- phase 2: scores S = mfma(Q, K^T) over dh=64 ----------
    f32x4 S[2];
#pragma unroll
    for (int s = 0; s < 2; ++s) {
        int pair = wv * 2 + s, win = pair >> 1, h = pair & 1;
        f32x4 z = {0.f, 0.f, 0.f, 0.f};
        int tok = win * 16 + l15;
#pragma unroll
        for (int kf = 0; kf < 2; ++kf) {
            int byte = tok * 256 + ((h * 128 + kf * 64 + q4 * 16) ^ xa);
            bf16x8 aq = ldsfrag(qls, byte);
            bf16x8 bk = ldsfrag(kls, byte);
            z = MFMA(aq, bk, z);
        }
        S[s] = z;
    }
    __syncthreads();

    // ---------- softmax in-register, P (bf16, K padded to 32) overlays qls ----------
#pragma unroll
    for (int s = 0; s < 2; ++s) {
        int pair = wv * 2 + s, win = pair >> 1, h = pair & 1;
#pragma unroll
        for (int r = 0; r < 4; ++r) {
            float v = S[s][r];
            float m = v;
            m = fmaxf(m, __shfl_xor(m, 1, 16)); m = fmaxf(m, __shfl_xor(m, 2, 16));
            m = fmaxf(m, __shfl_xor(m, 4, 16)); m = fmaxf(m, __shfl_xor(m, 8, 16));
            float e = __builtin_amdgcn_exp2f((v - m) * 1.44269504f);
            float sm = e;
            sm += __shfl_xor(sm, 1, 16); sm += __shfl_xor(sm, 2, 16);
            sm += __shfl_xor(sm, 4, 16); sm += __shfl_xor(sm, 8, 16);
            float p = e * __builtin_amdgcn_rcpf(sm);
            int tok = win * 16 + q4 * 4 + r, tx = (tok & 7) << 4;
            qls[(tok * 128 + ((h * 64 + l15 * 2)      ^ tx)) >> 1] = f2bf(p);
            qls[(tok * 128 + ((h * 64 + 32 + l15 * 2) ^ tx)) >> 1] = 0;
        }
    }
    __syncthreads();

    // ---------- phase 3: PV -> xs ----------
#pragma unroll
    for (int s = 0; s < 2; ++s) {
        int pair = wv * 2 + s, win = pair >> 1, h = pair & 1;
        bf16x8 ap = ldsfrag(qls, (win * 16 + l15) * 128 + ((h * 64 + q4 * 16) ^ xa));
#pragma unroll
        for (int nf = 0; nf < 4; ++nf) {
            int dh = h * 64 + nf * 16 + l15;
            bf16x8 bv = ldsfrag(vt, dh * 384 + ((win * 32 + q4 * 16) ^ xa));
            f32x4 z = {0.f, 0.f, 0.f, 0.f};
            f32x4 o = MFMA(ap, bv, z);
#pragma unroll
            for (int r = 0; r < 4; ++r) {
                int tok = win * 16 + q4 * 4 + r;
                xs[(tok * 256 + ((2 * dh) ^ ((tok & 7) << 4))) >> 1] = f2bf(o[r]);
            }
        }
    }
    __syncthreads();

    // ---------- phase 4: output projection + residual epilogue ----------
    {
        int n0 = wv * 16;
        float bias = ob[n0 + l15];
        f32x4 acc[8];
#pragma unroll
        for (int mf = 0; mf < 8; ++mf) acc[mf] = (f32x4){bias, bias, bias, bias};
#pragma unroll
        for (int kf = 0; kf < 4; ++kf) {
            bf16x8 bfr = ldg8(ow + (size_t)(n0 + l15) * 128 + kf * 32 + q4 * 8);
#pragma unroll
            for (int mf = 0; mf < 8; ++mf) {
                bf16x8 afr = ldsfrag(xs, (mf * 16 + l15) * 256 + ((kf * 64 + q4 * 16) ^ xa));
                acc[mf] = MFMA(afr, bfr, acc[mf]);
            }
        }
#pragma unroll
        for (int mf = 0; mf < 8; ++mf)
#pragma unroll
            for (int r = 0; r < 4; ++r) {
                int tok = mf * 16 + q4 * 4 + r;
                int nd = (BRANCH == 1) ? (wg * 128 + tok) : src_index<2>(wg, tok);
                size_t ridx = ((size_t)bb * 16384 + nd) * 128 + n0 + l15;
                float rv = resin[ridx];
                if (BRANCH == 1) rv = truncf(rv);
                resout[ridx] = rv + acc[mf][r];
            }
    }
}

// ---------------------------------------------------------------------------
// Fused MLP, in place. 1 block = 64 tokens, 4 waves. h1 chunked 4x128 cols:
// LDS 32 KiB -> 4 blocks/CU. GEMM2 accumulates partial K per chunk.
// ---------------------------------------------------------------------------
__global__ __launch_bounds__(256, 4)
void mlp_mfma(float* __restrict__ buf,
              const float* __restrict__ ln_g, const float* __restrict__ ln_b,
              const u16* __restrict__ w1, const float* __restrict__ b1,
              const u16* __restrict__ w2, const float* __restrict__ b2)
{
    __shared__ __align__(16) u16 xs [64 * 128];   // 16 KiB
    __shared__ __align__(16) u16 h1c[64 * 128];   // 16 KiB (one 128-col chunk)

    const int t = threadIdx.x;
    const int wv = t >> 6, ln = t & 63, l15 = ln & 15, q4 = ln >> 4;
    const int xa = (l15 & 7) << 4;
    const size_t base = (size_t)blockIdx.x * 64 * 128;

    // ---------- LN -> xs (bf16) ----------
    {
        int token = t >> 2, part = t & 3;
        const float* src = buf + base + token * 128 + part * 32;
        float v[32];
#pragma unroll
        for (int i = 0; i < 8; ++i) *(float4*)&v[i * 4] = ((const float4*)src)[i];
        float s = 0.f, s2 = 0.f;
#pragma unroll
        for (int i = 0; i < 32; ++i) { s += v[i]; s2 += v[i] * v[i]; }
        s  += __shfl_xor(s, 1, 4);  s  += __shfl_xor(s, 2, 4);
        s2 += __shfl_xor(s2, 1, 4); s2 += __shfl_xor(s2, 2, 4);
        float mu = s * (1.f / 128.f);
        float rstd = rsqrtf(s2 * (1.f / 128.f) - mu * mu + 1e-5f);
        int tx = (token & 7) << 4;
#pragma unroll
        for (int g = 0; g < 4; ++g) {
            uint4 u; u32* up = (u32*)&u;
#pragma unroll
            for (int j = 0; j < 4; ++j) {
                int d0 = part * 32 + g * 8 + j * 2;
                float a = (v[g * 8 + j * 2]     - mu) * rstd * ln_g[d0]     + ln_b[d0];
                float c = (v[g * 8 + j * 2 + 1] - mu) * rstd * ln_g[d0 + 1] + ln_b[d0 + 1];
                up[j] = (u32)f2bf(a) | ((u32)f2bf(c) << 16);
            }
            int byte = token * 256 + ((part * 64 + g * 16) ^ tx);
            *(uint4*)((char*)xs + byte) = u;
        }
    }
    __syncthreads();

    const int nb = wv * 32;                 // this wave's 32 cols (GEMM1-chunk & GEMM2-out)
    f32x4 acc2[4][2];
#pragma unroll
    for (int nf = 0; nf < 2; ++nf) {
        float bias = b2[nb + nf * 16 + l15];
#pragma unroll
        for (int mf = 0; mf < 4; ++mf) acc2[mf][nf] = (f32x4){bias, bias, bias, bias};
    }

#pragma unroll
    for (int c = 0; c < 4; ++c) {
        // ---- GEMM1 chunk: h1 cols [c*128, c*128+128), wave does 32 of them ----
        f32x4 acc1[4][2];
#pragma unroll
        for (int nf = 0; nf < 2; ++nf) {
            float bias = b1[c * 128 + nb + nf * 16 + l15];
#pragma unroll
            for (int mf = 0; mf < 4; ++mf) acc1[mf][nf] = (f32x4){bias, bias, bias, bias};
        }
#pragma unroll
        for (int kf = 0; kf < 4; ++kf) {
            bf16x8 a[4];
#pragma unroll
            for (int mf = 0; mf < 4; ++mf)
                a[mf] = ldsfrag(xs, (mf * 16 + l15) * 256 + ((kf * 64 + q4 * 16) ^ xa));
#pragma unroll
            for (int nf = 0; nf < 2; ++nf) {
                bf16x8 bfr = ldg8(w1 + (size_t)(c * 128 + nb + nf * 16 + l15) * 128 + kf * 32 + q4 * 8);
#pragma unroll
                for (int mf = 0; mf < 4; ++mf) acc1[mf][nf] = MFMA(a[mf], bfr, acc1[mf][nf]);
            }
        }
#pragma unroll
        for (int nf = 0; nf < 2; ++nf) {
            int lc = nb + nf * 16 + l15;       // chunk-local col
#pragma unroll
            for (int mf = 0; mf < 4; ++mf)
#pragma unroll
                for (int r = 0; r < 4; ++r) {
                    int tok = mf * 16 + q4 * 4 + r;
                    h1c[(tok * 256 + ((2 * lc) ^ ((tok & 7) << 4))) >> 1] =
                        f2bf(gelu_fast(acc1[mf][nf][r]));
                }
        }
        __syncthreads();
        // ---- GEMM2 partial: K rows [c*128, c*128+128) ----
#pragma unroll
        for (int kf = 0; kf < 4; ++kf) {
            bf16x8 a[4];
#pragma unroll
            for (int mf = 0; mf < 4; ++mf)
                a[mf] = ldsfrag(h1c, (mf * 16 + l15) * 256 + ((kf * 64 + q4 * 16) ^ xa));
#pragma unroll
            for (int nf = 0; nf < 2; ++nf) {
                bf16x8 bfr = ldg8(w2 + (size_t)(nb + nf * 16 + l15) * 512 + c * 128 + kf * 32 + q4 * 8);
#pragma unroll
                for (int mf = 0; mf < 4; ++mf) acc2[mf][nf] = MFMA(a[mf], bfr, acc2[mf][nf]);
            }
        }
        __syncthreads();
    }

    // ---------- epilogue: GELU + residual, in place ----------
#pragma unroll
    for (int nf = 0; nf < 2; ++nf) {
        int col = nb + nf * 16 + l15;
#pragma unroll
        for (int mf = 0; mf < 4; ++mf)
#pragma unroll
            for (int r = 0; r < 4; ++r) {
                int tok = mf * 16 + q4 * 4 + r;
                size_t idx = base + (size_t)tok * 128 + col;
                buf[idx] = gelu_fast(acc2[mf][nf][r]) + buf[idx];
            }
    }
}

extern "C" void kernel_launch(void* const* d_in, const int* in_sizes, int n_in,
                              void* d_out, int out_size, void* d_ws, size_t ws_size,
                              hipStream_t stream) {
    (void)in_sizes; (void)n_in; (void)out_size; (void)ws_size;
    const float* x      = (const float*)d_in[0];
    const float* ln1_g  = (const float*)d_in[1];
    const float* ln1_b  = (const float*)d_in[2];
    const float* ln2_g  = (const float*)d_in[3];
    const float* ln2_b  = (const float*)d_in[4];
    const float* ln3_g  = (const float*)d_in[5];
    const float* ln3_b  = (const float*)d_in[6];
    const float* ln4_g  = (const float*)d_in[7];
    const float* ln4_b  = (const float*)d_in[8];
    const float* qkv1_w = (const float*)d_in[9];
    const float* qkv1_b = (const float*)d_in[10];
    const float* out1_w = (const float*)d_in[11];
    const float* out1_b = (const float*)d_in[12];
    const float* qkv2_w = (const float*)d_in[13];
    const float* qkv2_b = (const float*)d_in[14];
    const float* out2_w = (const float*)d_in[15];
    const float* out2_b = (const float*)d_in[16];
    const float* mlp1_w1 = (const float*)d_in[17];
    const float* mlp1_b1 = (const float*)d_in[18];
    const float* mlp1_w2 = (const float*)d_in[19];
    const float* mlp1_b2 = (const float*)d_in[20];
    const float* mlp2_w1 = (const float*)d_in[21];
    const float* mlp2_b1 = (const float*)d_in[22];
    const float* mlp2_w2 = (const float*)d_in[23];
    const float* mlp2_b2 = (const float*)d_in[24];

    // bf16 weights in d_ws (786 KiB total)
    u16* wb = (u16*)d_ws;
    u16* qkv1bf = wb + 0;
    u16* out1bf = wb + 49152;
    u16* m1w1bf = wb + 65536;
    u16* m1w2bf = wb + 131072;
    u16* qkv2bf = wb + 196608;
    u16* out2bf = wb + 245760;
    u16* m2w1bf = wb + 262144;
    u16* m2w2bf = wb + 327680;

    float* out = (float*)d_out;   // activations: res1 -> out1 -> res2 -> out2, in place

    cvt_weights<<<dim3(192), dim3(256), 0, stream>>>(
        qkv1_w, out1_w, mlp1_w1, mlp1_w2, qkv2_w, out2_w, mlp2_w1, mlp2_w2, wb);

    // 1) W-MSA: res1 = trunc(x) + a1     (writes every element of d_out)
    attn_mfma<1><<<dim3(1024), dim3(512), 0, stream>>>(x, x, out,
        ln1_g, ln1_b, qkv1bf, qkv1_b, out1bf, out1_b);
    // 2) MLP1 (in place)
    mlp_mfma<<<dim3(2048), dim3(256), 0, stream>>>(out, ln2_g, ln2_b,
        m1w1bf, mlp1_b1, m1w2bf, mlp1_b2);
    // 3) SW-MSA: res2 = out1 + a2 (gather index == scatter index; block-local rows)
    attn_mfma<2><<<dim3(1024), dim3(512), 0, stream>>>(out, out, out,
        ln3_g, ln3_b, qkv2bf, qkv2_b, out2bf, out2_b);
    // 4) MLP2 (in place)
    mlp_mfma<<<dim3(2048), dim3(256), 0, stream>>>(out, ln4_g, ln4_b,
        m2w1bf, mlp2_b1, m2w2bf, mlp2_b2);
}